// Round 4
// baseline (4513.214 us; speedup 1.0000x reference)
//
#include <hip/hip_runtime.h>
#include <math.h>

#define N_NODES 100000
#define N_EDGES 1600000
#define F_IN 256
#define F_H 128
#define F_OUT 64

// ---------------------------------------------------------------------------
// degree / norm kernels
// ---------------------------------------------------------------------------
__global__ void deg_init(float* deg, int n) {
    int i = blockIdx.x * blockDim.x + threadIdx.x;
    if (i < n) deg[i] = 1.0f;  // self-loop contributes 1
}

__global__ void deg_count(const int* __restrict__ col, float* deg, int nE) {
    int e = blockIdx.x * blockDim.x + threadIdx.x;
    if (e < nE) atomicAdd(&deg[col[e]], 1.0f);
}

__global__ void deg_rsqrt(float* deg, int n) {
    int i = blockIdx.x * blockDim.x + threadIdx.x;
    if (i < n) deg[i] = rsqrtf(deg[i]);  // deg >= 1 always (self-loop)
}

// ---------------------------------------------------------------------------
// tiled fp32 GEMM:  H[M x BN] = (relu?)(X[M x K]) @ W[K x BN]
// BM=64, BK=32, 256 threads. CPT = BN/32 cols per thread.
// ---------------------------------------------------------------------------
template <int K, int BN, int CPT, bool RELU>
__global__ __launch_bounds__(256) void gemm_k(const float* __restrict__ X,
                                              const float* __restrict__ W,
                                              float* __restrict__ H, int M) {
    __shared__ float sX[64][33];   // +1 pad
    __shared__ float sW[32][BN];
    const int tid = threadIdx.x;
    const int tx = tid & 31, ty = tid >> 5;
    const int m0 = blockIdx.x * 64;

    float acc[8][CPT];
#pragma unroll
    for (int m = 0; m < 8; m++)
#pragma unroll
        for (int i = 0; i < CPT; i++) acc[m][i] = 0.0f;

    for (int k0 = 0; k0 < K; k0 += 32) {
        // X tile: 64x32
#pragma unroll
        for (int i = 0; i < 8; i++) {
            int idx = tid + i * 256;
            int r = idx >> 5, c = idx & 31;
            int gr = m0 + r;
            float v = (gr < M) ? X[gr * K + k0 + c] : 0.0f;
            if (RELU) v = fmaxf(v, 0.0f);
            sX[r][c] = v;
        }
        // W tile: 32xBN
#pragma unroll
        for (int i = 0; i < (32 * BN) / 256; i++) {
            int idx = tid + i * 256;
            int r = idx / BN, c = idx % BN;
            sW[r][c] = W[(k0 + r) * BN + c];
        }
        __syncthreads();
#pragma unroll
        for (int k = 0; k < 32; k++) {
            float a[8], b[CPT];
#pragma unroll
            for (int m = 0; m < 8; m++) a[m] = sX[ty * 8 + m][k];
#pragma unroll
            for (int i = 0; i < CPT; i++) b[i] = sW[k][tx + i * 32];
#pragma unroll
            for (int m = 0; m < 8; m++)
#pragma unroll
                for (int i = 0; i < CPT; i++)
                    acc[m][i] = fmaf(a[m], b[i], acc[m][i]);
        }
        __syncthreads();
    }
#pragma unroll
    for (int m = 0; m < 8; m++) {
        int gr = m0 + ty * 8 + m;
        if (gr < M) {
#pragma unroll
            for (int i = 0; i < CPT; i++) H[gr * BN + tx + i * 32] = acc[m][i];
        }
    }
}

// ---------------------------------------------------------------------------
// out[i][:] = bias + h[i][:] * dis[i]^2   (self-loop message + bias init)
// F4 = features/4
// ---------------------------------------------------------------------------
template <int F4>
__global__ void selfloop_init(const float* __restrict__ H,
                              const float* __restrict__ dis,
                              const float* __restrict__ bias, float* out, int M) {
    int tid = blockIdx.x * blockDim.x + threadIdx.x;
    if (tid >= M * F4) return;
    int i = tid / F4;
    int c = tid % F4;
    float d = dis[i];
    float n = d * d;
    float4 h = ((const float4*)H)[tid];
    float4 b = ((const float4*)bias)[c];
    float4 o;
    o.x = b.x + h.x * n;
    o.y = b.y + h.y * n;
    o.z = b.z + h.z * n;
    o.w = b.w + h.w * n;
    ((float4*)out)[tid] = o;
}

// ---------------------------------------------------------------------------
// edge aggregation with fp32 atomics. F4C = features/4 chunks per edge (pow2)
// LOG2F4C so we can use shifts.
// ---------------------------------------------------------------------------
template <int LOG2F4C>
__global__ void agg_edges(const int* __restrict__ row, const int* __restrict__ col,
                          const float* __restrict__ dis,
                          const float* __restrict__ H, float* out) {
    const int F4C = 1 << LOG2F4C;
    int tid = blockIdx.x * blockDim.x + threadIdx.x;
    int e = tid >> LOG2F4C;
    int c = tid & (F4C - 1);
    if (e >= N_EDGES) return;
    int r = row[e], cl = col[e];
    float nrm = dis[r] * dis[cl];
    float4 v = ((const float4*)H)[r * F4C + c];
    float* o = out + (size_t)cl * (F4C * 4) + c * 4;
    atomicAdd(o + 0, v.x * nrm);
    atomicAdd(o + 1, v.y * nrm);
    atomicAdd(o + 2, v.z * nrm);
    atomicAdd(o + 3, v.w * nrm);
}

// ---------------------------------------------------------------------------
// in-place log_softmax over rows of 64. One wave per row.
// ---------------------------------------------------------------------------
__global__ void log_softmax64(float* out, int M) {
    int row = blockIdx.x * 4 + (threadIdx.x >> 6);
    int lane = threadIdx.x & 63;
    if (row >= M) return;
    float v = out[row * 64 + lane];
    float m = v;
#pragma unroll
    for (int mask = 32; mask >= 1; mask >>= 1) m = fmaxf(m, __shfl_xor(m, mask));
    float ex = __expf(v - m);
    float s = ex;
#pragma unroll
    for (int mask = 32; mask >= 1; mask >>= 1) s += __shfl_xor(s, mask);
    out[row * 64 + lane] = v - m - logf(s);
}

// ---------------------------------------------------------------------------
extern "C" void kernel_launch(void* const* d_in, const int* in_sizes, int n_in,
                              void* d_out, int out_size, void* d_ws, size_t ws_size,
                              hipStream_t stream) {
    const float* x  = (const float*)d_in[0];
    const int*   ei = (const int*)d_in[1];
    const float* W1 = (const float*)d_in[2];
    const float* b1 = (const float*)d_in[3];
    const float* W2 = (const float*)d_in[4];
    const float* b2 = (const float*)d_in[5];
    float* out = (float*)d_out;

    const int* row = ei;             // edge_index[0]
    const int* col = ei + N_EDGES;   // edge_index[1]

    char* base = (char*)d_ws;
    float* dis = (float*)(base);                       // 100000 f -> 400,000 B
    float* h1  = (float*)(base + 400000);              // 12.8M f  -> 51.2 MB
    float* o1  = (float*)(base + 51600000);            // 12.8M f  -> 51.2 MB
    float* h2  = (float*)(base + 102800000);           // 6.4M  f  -> 25.6 MB

    // degree -> rsqrt
    deg_init<<<(N_NODES + 255) / 256, 256, 0, stream>>>(dis, N_NODES);
    deg_count<<<(N_EDGES + 255) / 256, 256, 0, stream>>>(col, dis, N_EDGES);
    deg_rsqrt<<<(N_NODES + 255) / 256, 256, 0, stream>>>(dis, N_NODES);

    // layer 1: h1 = x @ W1
    gemm_k<F_IN, F_H, 4, false><<<(N_NODES + 63) / 64, 256, 0, stream>>>(x, W1, h1, N_NODES);
    // o1 = b1 + selfloop + scatter(h1[row]*norm -> col)
    selfloop_init<F_H / 4><<<(N_NODES * (F_H / 4) + 255) / 256, 256, 0, stream>>>(h1, dis, b1, o1, N_NODES);
    agg_edges<5><<<(N_EDGES * (F_H / 4) + 255) / 256, 256, 0, stream>>>(row, col, dis, h1, o1);

    // layer 2: h2 = relu(o1) @ W2
    gemm_k<F_H, F_OUT, 2, true><<<(N_NODES + 63) / 64, 256, 0, stream>>>(o1, W2, h2, N_NODES);
    selfloop_init<F_OUT / 4><<<(N_NODES * (F_OUT / 4) + 255) / 256, 256, 0, stream>>>(h2, dis, b2, out, N_NODES);
    agg_edges<4><<<(N_EDGES * (F_OUT / 4) + 255) / 256, 256, 0, stream>>>(row, col, dis, h2, out);

    // log softmax in place on d_out
    log_softmax64<<<(N_NODES + 3) / 4, 256, 0, stream>>>(out, N_NODES);
}

// Round 6
// 889.287 us; speedup vs baseline: 5.0751x; 5.0751x over previous
//
#include <hip/hip_runtime.h>
#include <math.h>

#define N_NODES 100000
#define N_EDGES 1600000
#define F_IN 256
#define F_H 128
#define F_OUT 64
#define SCAN_B 256

// ---------------------------------------------------------------------------
// CSR build: count -> scan -> scatter
// ---------------------------------------------------------------------------
__global__ void zero_i32(int* p, int n) {
    int i = blockIdx.x * blockDim.x + threadIdx.x;
    if (i < n) p[i] = 0;
}

__global__ void count_in(const int* __restrict__ col, int* cnt, int nE) {
    int e = blockIdx.x * blockDim.x + threadIdx.x;
    if (e < nE) atomicAdd(&cnt[col[e]], 1);
}

// per-block exclusive scan (Hillis-Steele in LDS) + block totals
__global__ __launch_bounds__(SCAN_B) void scan1(const int* __restrict__ cnt,
                                                int* pre, int* bsum, int n) {
    __shared__ int tmp[SCAN_B];
    int i = blockIdx.x * SCAN_B + threadIdx.x;
    int v = (i < n) ? cnt[i] : 0;
    tmp[threadIdx.x] = v;
    __syncthreads();
#pragma unroll
    for (int off = 1; off < SCAN_B; off <<= 1) {
        int t = (threadIdx.x >= off) ? tmp[threadIdx.x - off] : 0;
        __syncthreads();
        tmp[threadIdx.x] += t;
        __syncthreads();
    }
    if (i < n) pre[i] = tmp[threadIdx.x] - v;  // exclusive within block
    if (threadIdx.x == SCAN_B - 1) bsum[blockIdx.x] = tmp[threadIdx.x];
}

// serial exclusive scan of block sums (nb ~ 391, trivial)
__global__ void scan2(int* bsum, int nb) {
    if (blockIdx.x == 0 && threadIdx.x == 0) {
        int run = 0;
        for (int i = 0; i < nb; i++) { int v = bsum[i]; bsum[i] = run; run += v; }
    }
}

// final offsets + cursor copy + dis = rsqrt(deg) fused
__global__ void scan3(const int* __restrict__ pre, const int* __restrict__ bsum,
                      const int* __restrict__ cnt, int* off, int* cursor,
                      float* dis, int n) {
    int i = blockIdx.x * SCAN_B + threadIdx.x;
    if (i < n) {
        int o = pre[i] + bsum[blockIdx.x];
        off[i] = o;
        cursor[i] = o;
        dis[i] = rsqrtf((float)cnt[i] + 1.0f);  // +1 self-loop
    }
}

__global__ void csr_fill(const int* __restrict__ row, const int* __restrict__ col,
                         int* cursor, int* src, int nE) {
    int e = blockIdx.x * blockDim.x + threadIdx.x;
    if (e < nE) {
        int c = col[e];
        int p = atomicAdd(&cursor[c], 1);
        src[p] = row[e];
    }
}

// ---------------------------------------------------------------------------
// tiled fp32 GEMM:  H[M x BN] = (relu?)(X[M x K]) @ W[K x BN]
// BM=64, BK=32, 256 threads. CPT = BN/32 cols per thread.
// ---------------------------------------------------------------------------
template <int K, int BN, int CPT, bool RELU>
__global__ __launch_bounds__(256) void gemm_k(const float* __restrict__ X,
                                              const float* __restrict__ W,
                                              float* __restrict__ H, int M) {
    __shared__ float sX[64][33];   // +1 pad
    __shared__ float sW[32][BN];
    const int tid = threadIdx.x;
    const int tx = tid & 31, ty = tid >> 5;
    const int m0 = blockIdx.x * 64;

    float acc[8][CPT];
#pragma unroll
    for (int m = 0; m < 8; m++)
#pragma unroll
        for (int i = 0; i < CPT; i++) acc[m][i] = 0.0f;

    for (int k0 = 0; k0 < K; k0 += 32) {
#pragma unroll
        for (int i = 0; i < 8; i++) {
            int idx = tid + i * 256;
            int r = idx >> 5, c = idx & 31;
            int gr = m0 + r;
            float v = (gr < M) ? X[gr * K + k0 + c] : 0.0f;
            if (RELU) v = fmaxf(v, 0.0f);
            sX[r][c] = v;
        }
#pragma unroll
        for (int i = 0; i < (32 * BN) / 256; i++) {
            int idx = tid + i * 256;
            int r = idx / BN, c = idx % BN;
            sW[r][c] = W[(k0 + r) * BN + c];
        }
        __syncthreads();
#pragma unroll
        for (int k = 0; k < 32; k++) {
            float a[8], b[CPT];
#pragma unroll
            for (int m = 0; m < 8; m++) a[m] = sX[ty * 8 + m][k];
#pragma unroll
            for (int i = 0; i < CPT; i++) b[i] = sW[k][tx + i * 32];
#pragma unroll
            for (int m = 0; m < 8; m++)
#pragma unroll
                for (int i = 0; i < CPT; i++)
                    acc[m][i] = fmaf(a[m], b[i], acc[m][i]);
        }
        __syncthreads();
    }
#pragma unroll
    for (int m = 0; m < 8; m++) {
        int gr = m0 + ty * 8 + m;
        if (gr < M) {
#pragma unroll
            for (int i = 0; i < CPT; i++) H[gr * BN + tx + i * 32] = acc[m][i];
        }
    }
}

// ---------------------------------------------------------------------------
// CSR gather aggregation. F4 = features/4 (float4 lanes per node).
// out[i] = bias + dis_i * ( dis_i*h_i + sum_{e in in(i)} dis_src*h_src )
// ---------------------------------------------------------------------------
template <int F4>
__global__ __launch_bounds__(256) void gather_agg(const int* __restrict__ off,
                                                  const int* __restrict__ src,
                                                  const float* __restrict__ dis,
                                                  const float* __restrict__ H,
                                                  const float* __restrict__ bias,
                                                  float* __restrict__ out) {
    const int npb = 256 / F4;
    int node = blockIdx.x * npb + threadIdx.x / F4;
    int f = threadIdx.x & (F4 - 1);
    if (node >= N_NODES) return;
    int s = off[node];
    int e = (node == N_NODES - 1) ? N_EDGES : off[node + 1];
    float di = dis[node];
    const float4* H4 = (const float4*)H;
    float4 h = H4[(size_t)node * F4 + f];
    float4 acc;
    acc.x = di * h.x; acc.y = di * h.y; acc.z = di * h.z; acc.w = di * h.w;
    for (int k = s; k < e; k++) {
        int sn = src[k];
        float ds = dis[sn];
        float4 v = H4[(size_t)sn * F4 + f];
        acc.x = fmaf(ds, v.x, acc.x);
        acc.y = fmaf(ds, v.y, acc.y);
        acc.z = fmaf(ds, v.z, acc.z);
        acc.w = fmaf(ds, v.w, acc.w);
    }
    float4 b = ((const float4*)bias)[f];
    float4 o;
    o.x = fmaf(di, acc.x, b.x);
    o.y = fmaf(di, acc.y, b.y);
    o.z = fmaf(di, acc.z, b.z);
    o.w = fmaf(di, acc.w, b.w);
    ((float4*)out)[(size_t)node * F4 + f] = o;
}

// ---------------------------------------------------------------------------
// in-place log_softmax over rows of 64. One wave per row.
// ---------------------------------------------------------------------------
__global__ void log_softmax64(float* out, int M) {
    int row = blockIdx.x * 4 + (threadIdx.x >> 6);
    int lane = threadIdx.x & 63;
    if (row >= M) return;
    float v = out[row * 64 + lane];
    float m = v;
#pragma unroll
    for (int mask = 32; mask >= 1; mask >>= 1) m = fmaxf(m, __shfl_xor(m, mask));
    float ex = __expf(v - m);
    float s = ex;
#pragma unroll
    for (int mask = 32; mask >= 1; mask >>= 1) s += __shfl_xor(s, mask);
    out[row * 64 + lane] = v - m - logf(s);
}

// ---------------------------------------------------------------------------
extern "C" void kernel_launch(void* const* d_in, const int* in_sizes, int n_in,
                              void* d_out, int out_size, void* d_ws, size_t ws_size,
                              hipStream_t stream) {
    const float* x  = (const float*)d_in[0];
    const int*   ei = (const int*)d_in[1];
    const float* W1 = (const float*)d_in[2];
    const float* b1 = (const float*)d_in[3];
    const float* W2 = (const float*)d_in[4];
    const float* b2 = (const float*)d_in[5];
    float* out = (float*)d_out;

    const int* row = ei;             // edge_index[0]
    const int* col = ei + N_EDGES;   // edge_index[1]

    // workspace layout (bytes)
    char* base = (char*)d_ws;
    float* dis   = (float*)(base + 0);          //   400,000
    int*   cnt   = (int*)  (base + 400000);     //   400,000
    int*   pre   = (int*)  (base + 800000);     //   400,000
    int*   off   = (int*)  (base + 1200000);    //   400,000
    int*   curs  = (int*)  (base + 1600000);    //   400,000
    int*   bsum  = (int*)  (base + 2000000);    //     4,000 (391 used)
    int*   srcA  = (int*)  (base + 2004000);    // 6,400,000
    float* h1    = (float*)(base + 8404000);    // 51,200,000 (16B aligned)
    float* o1    = (float*)(base + 59604000);   // 51,200,000 (16B aligned)
    float* h2    = h1;                          // alias: h1 dead after gather1
    // total: ~110.8 MB

    const int NB_N = (N_NODES + SCAN_B - 1) / SCAN_B;   // 391
    const int NB_E = (N_EDGES + 255) / 256;             // 6250

    // --- CSR build (once per launch, reused by both layers) ---
    zero_i32<<<NB_N, 256, 0, stream>>>(cnt, N_NODES);
    count_in<<<NB_E, 256, 0, stream>>>(col, cnt, N_EDGES);
    scan1<<<NB_N, SCAN_B, 0, stream>>>(cnt, pre, bsum, N_NODES);
    scan2<<<1, 64, 0, stream>>>(bsum, NB_N);
    scan3<<<NB_N, SCAN_B, 0, stream>>>(pre, bsum, cnt, off, curs, dis, N_NODES);
    csr_fill<<<NB_E, 256, 0, stream>>>(row, col, curs, srcA, N_EDGES);

    // --- layer 1: h1 = x @ W1 ; o1 = agg(h1) ---
    gemm_k<F_IN, F_H, 4, false><<<(N_NODES + 63) / 64, 256, 0, stream>>>(x, W1, h1, N_NODES);
    gather_agg<F_H / 4><<<(N_NODES + 7) / 8, 256, 0, stream>>>(off, srcA, dis, h1, b1, o1);

    // --- layer 2: h2 = relu(o1) @ W2 ; out = agg(h2) ---
    gemm_k<F_H, F_OUT, 2, true><<<(N_NODES + 63) / 64, 256, 0, stream>>>(o1, W2, h2, N_NODES);
    gather_agg<F_OUT / 4><<<(N_NODES + 15) / 16, 256, 0, stream>>>(off, srcA, dis, h2, b2, out);

    // --- log softmax in place on d_out ---
    log_softmax64<<<(N_NODES + 3) / 4, 256, 0, stream>>>(out, N_NODES);
}

// Round 8
// 685.536 us; speedup vs baseline: 6.5835x; 1.2972x over previous
//
#include <hip/hip_runtime.h>
#include <math.h>

#define N_NODES 100000
#define N_EDGES 1600000
#define F_IN 256
#define F_H 128
#define F_OUT 64
#define SCAN_B 256

typedef float f32x4 __attribute__((ext_vector_type(4)));
typedef short s16x8 __attribute__((ext_vector_type(8)));

__device__ inline short f2bf(float f) {
    unsigned u = __builtin_bit_cast(unsigned, f);
    unsigned r = (u + 0x7FFFu + ((u >> 16) & 1u)) >> 16;
    return (short)r;
}

// ---------------------------------------------------------------------------
// CSR build: count -> scan -> scatter
// ---------------------------------------------------------------------------
__global__ void zero_i32(int* p, int n) {
    int i = blockIdx.x * blockDim.x + threadIdx.x;
    if (i < n) p[i] = 0;
}

__global__ void count_in(const int* __restrict__ col, int* cnt, int nE) {
    int e = blockIdx.x * blockDim.x + threadIdx.x;
    if (e < nE) atomicAdd(&cnt[col[e]], 1);
}

__global__ __launch_bounds__(SCAN_B) void scan1(const int* __restrict__ cnt,
                                                int* pre, int* bsum, int n) {
    __shared__ int tmp[SCAN_B];
    int i = blockIdx.x * SCAN_B + threadIdx.x;
    int v = (i < n) ? cnt[i] : 0;
    tmp[threadIdx.x] = v;
    __syncthreads();
#pragma unroll
    for (int off = 1; off < SCAN_B; off <<= 1) {
        int t = (threadIdx.x >= off) ? tmp[threadIdx.x - off] : 0;
        __syncthreads();
        tmp[threadIdx.x] += t;
        __syncthreads();
    }
    if (i < n) pre[i] = tmp[threadIdx.x] - v;
    if (threadIdx.x == SCAN_B - 1) bsum[blockIdx.x] = tmp[threadIdx.x];
}

__global__ void scan2(int* bsum, int nb) {
    if (blockIdx.x == 0 && threadIdx.x == 0) {
        int run = 0;
        for (int i = 0; i < nb; i++) { int v = bsum[i]; bsum[i] = run; run += v; }
    }
}

__global__ void scan3(const int* __restrict__ pre, const int* __restrict__ bsum,
                      const int* __restrict__ cnt, int* off, int* cursor,
                      float* dis, int n) {
    int i = blockIdx.x * SCAN_B + threadIdx.x;
    if (i < n) {
        int o = pre[i] + bsum[blockIdx.x];
        off[i] = o;
        cursor[i] = o;
        dis[i] = rsqrtf((float)cnt[i] + 1.0f);
    }
}

__global__ void csr_fill(const int* __restrict__ row, const int* __restrict__ col,
                         int* cursor, int* src, int nE) {
    int e = blockIdx.x * blockDim.x + threadIdx.x;
    if (e < nE) {
        int c = col[e];
        int p = atomicAdd(&cursor[c], 1);
        src[p] = row[e];
    }
}

// ---------------------------------------------------------------------------
// W prep: fp32 row-major [K][BN] -> bf16 chunked layout [kq][n][8]
// where k = kq*8 + j. Wt1 chunks: 32*128 = 4096; Wt2: 16*64 = 1024.
// ---------------------------------------------------------------------------
__global__ void prep_w(const float* __restrict__ W1, const float* __restrict__ W2,
                       short* __restrict__ Wt1, short* __restrict__ Wt2) {
    int u = blockIdx.x * blockDim.x + threadIdx.x;
    if (u < 4096) {
        int kq = u >> 7, n = u & 127;
        s16x8 p;
#pragma unroll
        for (int j = 0; j < 8; j++) p[j] = f2bf(W1[(kq * 8 + j) * 128 + n]);
        *(s16x8*)&Wt1[u * 8] = p;
    } else if (u < 5120) {
        int v = u - 4096;
        int kq = v >> 6, n = v & 63;
        s16x8 p;
#pragma unroll
        for (int j = 0; j < 8; j++) p[j] = f2bf(W2[(kq * 8 + j) * 64 + n]);
        *(s16x8*)&Wt2[v * 8] = p;
    }
}

// ---------------------------------------------------------------------------
// bf16 MFMA GEMM: H[M x BN] = (relu?)(X[M x K]) @ W[K x BN]
// BM=128 rows/block, 4 waves; wave w owns cols [w*BN/4, (w+1)*BN/4).
// Whole Wt in LDS (chunked [kq][n][8], linear copy). A staged per K-step in
// chunked [c][m][8] layout -> all fragment reads are linear ds_read_b128.
// Fragment k-order: lane group g = lane>>4 takes k = ks*32 + g*8 + j for BOTH
// A and B (identical q-function => correct for any HW within-frag k spec).
// C/D: col = lane&15, row = (lane>>4)*4 + reg  [HW-verified mapping].
// ---------------------------------------------------------------------------
template <int K, int BN, bool RELU>
__global__ __launch_bounds__(256) void gemm_mfma(const float* __restrict__ X,
                                                 const short* __restrict__ Wt,
                                                 float* __restrict__ H, int M) {
    constexpr int CF = BN / 64;     // 16-col fragments per wave (128->2, 64->1)
    constexpr int NKS = K / 32;
    __shared__ __align__(16) short sW[NKS * 4 * BN * 8];  // [kq][n][8]
    __shared__ __align__(16) short sA[4 * 128 * 8];       // [c][m][8]

    const int tid = threadIdx.x;
    const int wave = tid >> 6, lane = tid & 63;
    const int g = lane >> 4, fr = lane & 15;
    const int m0 = blockIdx.x * 128;
    const int wcol = wave * (BN / 4);

    // stage whole W: straight linear 16B copy
    {
        const f32x4* s = (const f32x4*)Wt;
        f32x4* d = (f32x4*)sW;
#pragma unroll 4
        for (int i = tid; i < (K * BN) / 8; i += 256) d[i] = s[i];
    }

    f32x4 acc[8][CF];
#pragma unroll
    for (int rf = 0; rf < 8; rf++)
#pragma unroll
        for (int cf = 0; cf < CF; cf++) {
            f32x4 z = {0.0f, 0.0f, 0.0f, 0.0f};
            acc[rf][cf] = z;
        }

    for (int ks = 0; ks < NKS; ks++) {
        __syncthreads();  // sA reuse guard (and W-copy guard on first iter)
        // stage A tile 128x32 fp32 -> bf16 chunked [c][m][8]
#pragma unroll
        for (int s = 0; s < 2; s++) {
            int u = tid + s * 256;     // 0..511
            int m = u >> 2, c = u & 3;
            int gr = m0 + m;
            float4 f0 = {0.f, 0.f, 0.f, 0.f}, f1 = {0.f, 0.f, 0.f, 0.f};
            if (gr < M) {
                const float4* xp = (const float4*)(X + (size_t)gr * K + ks * 32 + c * 8);
                f0 = xp[0];
                f1 = xp[1];
            }
            if (RELU) {
                f0.x = fmaxf(f0.x, 0.f); f0.y = fmaxf(f0.y, 0.f);
                f0.z = fmaxf(f0.z, 0.f); f0.w = fmaxf(f0.w, 0.f);
                f1.x = fmaxf(f1.x, 0.f); f1.y = fmaxf(f1.y, 0.f);
                f1.z = fmaxf(f1.z, 0.f); f1.w = fmaxf(f1.w, 0.f);
            }
            s16x8 p;
            p[0] = f2bf(f0.x); p[1] = f2bf(f0.y); p[2] = f2bf(f0.z); p[3] = f2bf(f0.w);
            p[4] = f2bf(f1.x); p[5] = f2bf(f1.y); p[6] = f2bf(f1.z); p[7] = f2bf(f1.w);
            *(s16x8*)&sA[(c * 128 + m) * 8] = p;
        }
        __syncthreads();

        // fragments: lane group g uses k-chunk g of this K-step
        s16x8 afr[8];
#pragma unroll
        for (int rf = 0; rf < 8; rf++)
            afr[rf] = *(const s16x8*)&sA[(g * 128 + rf * 16 + fr) * 8];
#pragma unroll
        for (int cf = 0; cf < CF; cf++) {
            int kq = ks * 4 + g;
            int n = wcol + cf * 16 + fr;
            s16x8 bfr = *(const s16x8*)&sW[(kq * BN + n) * 8];
#pragma unroll
            for (int rf = 0; rf < 8; rf++)
                acc[rf][cf] = __builtin_amdgcn_mfma_f32_16x16x32_bf16(
                    afr[rf], bfr, acc[rf][cf], 0, 0, 0);
        }
    }

    // epilogue: C/D row = g*4 + reg, col = fr
#pragma unroll
    for (int rf = 0; rf < 8; rf++) {
        int rowb = m0 + rf * 16 + g * 4;
#pragma unroll
        for (int r = 0; r < 4; r++) {
            int row = rowb + r;
            if (row < M) {
#pragma unroll
                for (int cf = 0; cf < CF; cf++)
                    H[(size_t)row * BN + wcol + cf * 16 + fr] = acc[rf][cf][r];
            }
        }
    }
}

// ---------------------------------------------------------------------------
// CSR gather aggregation. F4 = features/4 (float4 lanes per node).
// out[i] = bias + dis_i * ( dis_i*h_i + sum_{e in in(i)} dis_src*h_src )
// ---------------------------------------------------------------------------
template <int F4>
__global__ __launch_bounds__(256) void gather_agg(const int* __restrict__ off,
                                                  const int* __restrict__ src,
                                                  const float* __restrict__ dis,
                                                  const float* __restrict__ H,
                                                  const float* __restrict__ bias,
                                                  float* __restrict__ out) {
    const int npb = 256 / F4;
    int node = blockIdx.x * npb + threadIdx.x / F4;
    int f = threadIdx.x & (F4 - 1);
    if (node >= N_NODES) return;
    int s = off[node];
    int e = (node == N_NODES - 1) ? N_EDGES : off[node + 1];
    float di = dis[node];
    const float4* H4 = (const float4*)H;
    float4 h = H4[(size_t)node * F4 + f];
    float4 acc;
    acc.x = di * h.x; acc.y = di * h.y; acc.z = di * h.z; acc.w = di * h.w;
    for (int k = s; k < e; k++) {
        int sn = src[k];
        float ds = dis[sn];
        float4 v = H4[(size_t)sn * F4 + f];
        acc.x = fmaf(ds, v.x, acc.x);
        acc.y = fmaf(ds, v.y, acc.y);
        acc.z = fmaf(ds, v.z, acc.z);
        acc.w = fmaf(ds, v.w, acc.w);
    }
    float4 b = ((const float4*)bias)[f];
    float4 o;
    o.x = fmaf(di, acc.x, b.x);
    o.y = fmaf(di, acc.y, b.y);
    o.z = fmaf(di, acc.z, b.z);
    o.w = fmaf(di, acc.w, b.w);
    ((float4*)out)[(size_t)node * F4 + f] = o;
}

// ---------------------------------------------------------------------------
// in-place log_softmax over rows of 64. One wave per row.
// ---------------------------------------------------------------------------
__global__ void log_softmax64(float* out, int M) {
    int row = blockIdx.x * 4 + (threadIdx.x >> 6);
    int lane = threadIdx.x & 63;
    if (row >= M) return;
    float v = out[row * 64 + lane];
    float m = v;
#pragma unroll
    for (int mask = 32; mask >= 1; mask >>= 1) m = fmaxf(m, __shfl_xor(m, mask));
    float ex = __expf(v - m);
    float s = ex;
#pragma unroll
    for (int mask = 32; mask >= 1; mask >>= 1) s += __shfl_xor(s, mask);
    out[row * 64 + lane] = v - m - logf(s);
}

// ---------------------------------------------------------------------------
extern "C" void kernel_launch(void* const* d_in, const int* in_sizes, int n_in,
                              void* d_out, int out_size, void* d_ws, size_t ws_size,
                              hipStream_t stream) {
    const float* x  = (const float*)d_in[0];
    const int*   ei = (const int*)d_in[1];
    const float* W1 = (const float*)d_in[2];
    const float* b1 = (const float*)d_in[3];
    const float* W2 = (const float*)d_in[4];
    const float* b2 = (const float*)d_in[5];
    float* out = (float*)d_out;

    const int* row = ei;             // edge_index[0]
    const int* col = ei + N_EDGES;   // edge_index[1]

    // workspace layout (bytes)
    char* base = (char*)d_ws;
    float* dis   = (float*)(base + 0);          //   400,000
    int*   cnt   = (int*)  (base + 400000);
    int*   pre   = (int*)  (base + 800000);
    int*   off   = (int*)  (base + 1200000);
    int*   curs  = (int*)  (base + 1600000);
    int*   bsum  = (int*)  (base + 2000000);    //     4,000
    int*   srcA  = (int*)  (base + 2004000);    // 6,400,000
    short* Wt1   = (short*)(base + 8404000);    //    65,536 (16B aligned)
    short* Wt2   = (short*)(base + 8469536);    //    16,384 (16B aligned)
    float* h1    = (float*)(base + 8485920);    // 51,200,000 (16B aligned)
    float* o1    = (float*)(base + 59685920);   // 51,200,000 (16B aligned)
    float* h2    = h1;                          // alias: h1 dead after gather1
    // total ~110.9 MB

    const int NB_N = (N_NODES + SCAN_B - 1) / SCAN_B;   // 391
    const int NB_E = (N_EDGES + 255) / 256;             // 6250

    // --- CSR build + W prep ---
    zero_i32<<<NB_N, 256, 0, stream>>>(cnt, N_NODES);
    count_in<<<NB_E, 256, 0, stream>>>(col, cnt, N_EDGES);
    scan1<<<NB_N, SCAN_B, 0, stream>>>(cnt, pre, bsum, N_NODES);
    scan2<<<1, 64, 0, stream>>>(bsum, NB_N);
    scan3<<<NB_N, SCAN_B, 0, stream>>>(pre, bsum, cnt, off, curs, dis, N_NODES);
    csr_fill<<<NB_E, 256, 0, stream>>>(row, col, curs, srcA, N_EDGES);
    prep_w<<<20, 256, 0, stream>>>(W1, W2, Wt1, Wt2);

    const int NB_G = (N_NODES + 127) / 128;             // 782

    // --- layer 1: h1 = x @ W1 (bf16 MFMA) ; o1 = agg(h1) ---
    gemm_mfma<F_IN, F_H, false><<<NB_G, 256, 0, stream>>>(x, Wt1, h1, N_NODES);
    gather_agg<F_H / 4><<<(N_NODES + 7) / 8, 256, 0, stream>>>(off, srcA, dis, h1, b1, o1);

    // --- layer 2: h2 = relu(o1) @ W2 (bf16 MFMA) ; out = agg(h2) ---
    gemm_mfma<F_H, F_OUT, true><<<NB_G, 256, 0, stream>>>(o1, Wt2, h2, N_NODES);
    gather_agg<F_OUT / 4><<<(N_NODES + 15) / 16, 256, 0, stream>>>(off, srcA, dis, h2, b2, out);

    // --- log softmax in place on d_out ---
    log_softmax64<<<(N_NODES + 3) / 4, 256, 0, stream>>>(out, N_NODES);
}

// Round 9
// 555.028 us; speedup vs baseline: 8.1315x; 1.2351x over previous
//
#include <hip/hip_runtime.h>
#include <math.h>

#define N_NODES 100000
#define N_EDGES 1600000
#define F_IN 256
#define F_H 128
#define F_OUT 64
#define SCAN_B 256

typedef float f32x4 __attribute__((ext_vector_type(4)));
typedef short s16x8 __attribute__((ext_vector_type(8)));

__device__ inline short f2bf(float f) {
    unsigned u = __builtin_bit_cast(unsigned, f);
    unsigned r = (u + 0x7FFFu + ((u >> 16) & 1u)) >> 16;
    return (short)r;
}
__device__ inline float bf2f(short s) {
    return __builtin_bit_cast(float, ((unsigned)(unsigned short)s) << 16);
}

// ---------------------------------------------------------------------------
// CSR build: count -> scan -> scatter (packed {src, dis[src]} records)
// ---------------------------------------------------------------------------
__global__ void zero_i32(int* p, int n) {
    int i = blockIdx.x * blockDim.x + threadIdx.x;
    if (i < n) p[i] = 0;
}

__global__ void count_in(const int* __restrict__ col, int* cnt, int nE) {
    int e = blockIdx.x * blockDim.x + threadIdx.x;
    if (e < nE) atomicAdd(&cnt[col[e]], 1);
}

__global__ __launch_bounds__(SCAN_B) void scan1(const int* __restrict__ cnt,
                                                int* pre, int* bsum, int n) {
    __shared__ int tmp[SCAN_B];
    int i = blockIdx.x * SCAN_B + threadIdx.x;
    int v = (i < n) ? cnt[i] : 0;
    tmp[threadIdx.x] = v;
    __syncthreads();
#pragma unroll
    for (int off = 1; off < SCAN_B; off <<= 1) {
        int t = (threadIdx.x >= off) ? tmp[threadIdx.x - off] : 0;
        __syncthreads();
        tmp[threadIdx.x] += t;
        __syncthreads();
    }
    if (i < n) pre[i] = tmp[threadIdx.x] - v;
    if (threadIdx.x == SCAN_B - 1) bsum[blockIdx.x] = tmp[threadIdx.x];
}

__global__ void scan2(int* bsum, int nb) {
    if (blockIdx.x == 0 && threadIdx.x == 0) {
        int run = 0;
        for (int i = 0; i < nb; i++) { int v = bsum[i]; bsum[i] = run; run += v; }
    }
}

__global__ void scan3(const int* __restrict__ pre, const int* __restrict__ bsum,
                      const int* __restrict__ cnt, int* off, int* cursor,
                      float* dis, int n) {
    int i = blockIdx.x * SCAN_B + threadIdx.x;
    if (i < n) {
        int o = pre[i] + bsum[blockIdx.x];
        off[i] = o;
        cursor[i] = o;
        dis[i] = rsqrtf((float)cnt[i] + 1.0f);
    }
}

// packed record: {src_node, dis[src] bits}
__global__ void csr_fill(const int* __restrict__ row, const int* __restrict__ col,
                         const float* __restrict__ dis, int* cursor,
                         int2* __restrict__ recs, int nE) {
    int e = blockIdx.x * blockDim.x + threadIdx.x;
    if (e < nE) {
        int r = row[e];
        int c = col[e];
        int p = atomicAdd(&cursor[c], 1);
        recs[p] = make_int2(r, __float_as_int(dis[r]));
    }
}

// ---------------------------------------------------------------------------
// W prep: fp32 row-major [K][BN] -> bf16 chunked layout [kq][n][8]
// ---------------------------------------------------------------------------
__global__ void prep_w(const float* __restrict__ W1, const float* __restrict__ W2,
                       short* __restrict__ Wt1, short* __restrict__ Wt2) {
    int u = blockIdx.x * blockDim.x + threadIdx.x;
    if (u < 4096) {
        int kq = u >> 7, n = u & 127;
        s16x8 p;
#pragma unroll
        for (int j = 0; j < 8; j++) p[j] = f2bf(W1[(kq * 8 + j) * 128 + n]);
        *(s16x8*)&Wt1[u * 8] = p;
    } else if (u < 5120) {
        int v = u - 4096;
        int kq = v >> 6, n = v & 63;
        s16x8 p;
#pragma unroll
        for (int j = 0; j < 8; j++) p[j] = f2bf(W2[(kq * 8 + j) * 64 + n]);
        *(s16x8*)&Wt2[v * 8] = p;
    }
}

// ---------------------------------------------------------------------------
// bf16 MFMA GEMM: Hb[M x BN] (bf16) = (relu?)(X[M x K]) @ W[K x BN]
// identical structure to round-8 version; epilogue stores bf16.
// ---------------------------------------------------------------------------
template <int K, int BN, bool RELU>
__global__ __launch_bounds__(256) void gemm_mfma(const float* __restrict__ X,
                                                 const short* __restrict__ Wt,
                                                 unsigned short* __restrict__ Hb, int M) {
    constexpr int CF = BN / 64;
    constexpr int NKS = K / 32;
    __shared__ __align__(16) short sW[NKS * 4 * BN * 8];  // [kq][n][8]
    __shared__ __align__(16) short sA[4 * 128 * 8];       // [c][m][8]

    const int tid = threadIdx.x;
    const int wave = tid >> 6, lane = tid & 63;
    const int g = lane >> 4, fr = lane & 15;
    const int m0 = blockIdx.x * 128;
    const int wcol = wave * (BN / 4);

    {
        const f32x4* s = (const f32x4*)Wt;
        f32x4* d = (f32x4*)sW;
#pragma unroll 4
        for (int i = tid; i < (K * BN) / 8; i += 256) d[i] = s[i];
    }

    f32x4 acc[8][CF];
#pragma unroll
    for (int rf = 0; rf < 8; rf++)
#pragma unroll
        for (int cf = 0; cf < CF; cf++) {
            f32x4 z = {0.0f, 0.0f, 0.0f, 0.0f};
            acc[rf][cf] = z;
        }

    for (int ks = 0; ks < NKS; ks++) {
        __syncthreads();
#pragma unroll
        for (int s = 0; s < 2; s++) {
            int u = tid + s * 256;
            int m = u >> 2, c = u & 3;
            int gr = m0 + m;
            float4 f0 = {0.f, 0.f, 0.f, 0.f}, f1 = {0.f, 0.f, 0.f, 0.f};
            if (gr < M) {
                const float4* xp = (const float4*)(X + (size_t)gr * K + ks * 32 + c * 8);
                f0 = xp[0];
                f1 = xp[1];
            }
            if (RELU) {
                f0.x = fmaxf(f0.x, 0.f); f0.y = fmaxf(f0.y, 0.f);
                f0.z = fmaxf(f0.z, 0.f); f0.w = fmaxf(f0.w, 0.f);
                f1.x = fmaxf(f1.x, 0.f); f1.y = fmaxf(f1.y, 0.f);
                f1.z = fmaxf(f1.z, 0.f); f1.w = fmaxf(f1.w, 0.f);
            }
            s16x8 p;
            p[0] = f2bf(f0.x); p[1] = f2bf(f0.y); p[2] = f2bf(f0.z); p[3] = f2bf(f0.w);
            p[4] = f2bf(f1.x); p[5] = f2bf(f1.y); p[6] = f2bf(f1.z); p[7] = f2bf(f1.w);
            *(s16x8*)&sA[(c * 128 + m) * 8] = p;
        }
        __syncthreads();

        s16x8 afr[8];
#pragma unroll
        for (int rf = 0; rf < 8; rf++)
            afr[rf] = *(const s16x8*)&sA[(g * 128 + rf * 16 + fr) * 8];
#pragma unroll
        for (int cf = 0; cf < CF; cf++) {
            int kq = ks * 4 + g;
            int n = wcol + cf * 16 + fr;
            s16x8 bfr = *(const s16x8*)&sW[(kq * BN + n) * 8];
#pragma unroll
            for (int rf = 0; rf < 8; rf++)
                acc[rf][cf] = __builtin_amdgcn_mfma_f32_16x16x32_bf16(
                    afr[rf], bfr, acc[rf][cf], 0, 0, 0);
        }
    }

#pragma unroll
    for (int rf = 0; rf < 8; rf++) {
        int rowb = m0 + rf * 16 + g * 4;
#pragma unroll
        for (int r = 0; r < 4; r++) {
            int row = rowb + r;
            if (row < M) {
#pragma unroll
                for (int cf = 0; cf < CF; cf++)
                    Hb[(size_t)row * BN + wcol + cf * 16 + fr] =
                        (unsigned short)f2bf(acc[rf][cf][r]);
            }
        }
    }
}

// ---------------------------------------------------------------------------
// CSR gather aggregation over bf16 H. F8 = features/8 (bf16x8 = 16B per lane).
// out[i] = bias + dis_i * ( dis_i*h_i + sum recs{src,ds}: ds*h_src )  (fp32 out)
// ---------------------------------------------------------------------------
template <int F8>
__global__ __launch_bounds__(256) void gather_agg_bf(const int* __restrict__ off,
                                                     const int2* __restrict__ recs,
                                                     const float* __restrict__ dis,
                                                     const unsigned short* __restrict__ Hb,
                                                     const float* __restrict__ bias,
                                                     float* __restrict__ out) {
    const int npb = 256 / F8;
    int node = blockIdx.x * npb + threadIdx.x / F8;
    int f = threadIdx.x & (F8 - 1);
    if (node >= N_NODES) return;
    int s = off[node];
    int e = (node == N_NODES - 1) ? N_EDGES : off[node + 1];
    float di = dis[node];
    const s16x8* H8 = (const s16x8*)Hb;

    float acc[8];
    {
        s16x8 h = H8[(size_t)node * F8 + f];
#pragma unroll
        for (int j = 0; j < 8; j++) acc[j] = di * bf2f(h[j]);
    }
    for (int k = s; k < e; k++) {
        int2 rec = recs[k];
        float ds = __int_as_float(rec.y);
        s16x8 v = H8[(size_t)rec.x * F8 + f];
#pragma unroll
        for (int j = 0; j < 8; j++) acc[j] = fmaf(ds, bf2f(v[j]), acc[j]);
    }
    const f32x4* b4 = (const f32x4*)bias;
    f32x4 blo = b4[f * 2], bhi = b4[f * 2 + 1];
    f32x4 olo, ohi;
    olo.x = fmaf(di, acc[0], blo.x); olo.y = fmaf(di, acc[1], blo.y);
    olo.z = fmaf(di, acc[2], blo.z); olo.w = fmaf(di, acc[3], blo.w);
    ohi.x = fmaf(di, acc[4], bhi.x); ohi.y = fmaf(di, acc[5], bhi.y);
    ohi.z = fmaf(di, acc[6], bhi.z); ohi.w = fmaf(di, acc[7], bhi.w);
    f32x4* o4 = (f32x4*)out;
    size_t ob = ((size_t)node * F8 + f) * 2;
    o4[ob] = olo;
    o4[ob + 1] = ohi;
}

// ---------------------------------------------------------------------------
// in-place log_softmax over rows of 64. One wave per row.
// ---------------------------------------------------------------------------
__global__ void log_softmax64(float* out, int M) {
    int row = blockIdx.x * 4 + (threadIdx.x >> 6);
    int lane = threadIdx.x & 63;
    if (row >= M) return;
    float v = out[row * 64 + lane];
    float m = v;
#pragma unroll
    for (int mask = 32; mask >= 1; mask >>= 1) m = fmaxf(m, __shfl_xor(m, mask));
    float ex = __expf(v - m);
    float s = ex;
#pragma unroll
    for (int mask = 32; mask >= 1; mask >>= 1) s += __shfl_xor(s, mask);
    out[row * 64 + lane] = v - m - logf(s);
}

// ---------------------------------------------------------------------------
extern "C" void kernel_launch(void* const* d_in, const int* in_sizes, int n_in,
                              void* d_out, int out_size, void* d_ws, size_t ws_size,
                              hipStream_t stream) {
    const float* x  = (const float*)d_in[0];
    const int*   ei = (const int*)d_in[1];
    const float* W1 = (const float*)d_in[2];
    const float* b1 = (const float*)d_in[3];
    const float* W2 = (const float*)d_in[4];
    const float* b2 = (const float*)d_in[5];
    float* out = (float*)d_out;

    const int* row = ei;             // edge_index[0]
    const int* col = ei + N_EDGES;   // edge_index[1]

    // workspace layout (bytes)
    char* base = (char*)d_ws;
    float* dis   = (float*)(base + 0);           //    400,000
    int*   cnt   = (int*)  (base + 400000);
    int*   pre   = (int*)  (base + 800000);
    int*   off   = (int*)  (base + 1200000);
    int*   curs  = (int*)  (base + 1600000);
    int*   bsum  = (int*)  (base + 2000000);     //      4,000
    int2*  recs  = (int2*) (base + 2004000);     // 12,800,000 (8B aligned)
    short* Wt1   = (short*)(base + 14804000);    //     65,536 (16B aligned)
    short* Wt2   = (short*)(base + 14869536);    //     16,384
    unsigned short* h1b = (unsigned short*)(base + 14885920);  // 25,600,000 bf16
    float* o1    = (float*)(base + 40485920);    // 51,200,000 fp32
    unsigned short* h2b = h1b;                   // alias: h1b dead after gather1
    // total ~91.7 MB

    const int NB_N = (N_NODES + SCAN_B - 1) / SCAN_B;   // 391
    const int NB_E = (N_EDGES + 255) / 256;             // 6250

    // --- CSR build + W prep ---
    zero_i32<<<NB_N, 256, 0, stream>>>(cnt, N_NODES);
    count_in<<<NB_E, 256, 0, stream>>>(col, cnt, N_EDGES);
    scan1<<<NB_N, SCAN_B, 0, stream>>>(cnt, pre, bsum, N_NODES);
    scan2<<<1, 64, 0, stream>>>(bsum, NB_N);
    scan3<<<NB_N, SCAN_B, 0, stream>>>(pre, bsum, cnt, off, curs, dis, N_NODES);
    csr_fill<<<NB_E, 256, 0, stream>>>(row, col, dis, curs, recs, N_EDGES);
    prep_w<<<20, 256, 0, stream>>>(W1, W2, Wt1, Wt2);

    const int NB_G = (N_NODES + 127) / 128;             // 782

    // --- layer 1: h1b = bf16(x @ W1) ; o1 = agg(h1b) ---
    gemm_mfma<F_IN, F_H, false><<<NB_G, 256, 0, stream>>>(x, Wt1, h1b, N_NODES);
    gather_agg_bf<F_H / 8><<<(N_NODES + 15) / 16, 256, 0, stream>>>(off, recs, dis, h1b, b1, o1);

    // --- layer 2: h2b = bf16(relu(o1) @ W2) ; out = agg(h2b) ---
    gemm_mfma<F_H, F_OUT, true><<<NB_G, 256, 0, stream>>>(o1, Wt2, h2b, N_NODES);
    gather_agg_bf<F_OUT / 8><<<(N_NODES + 31) / 32, 256, 0, stream>>>(off, recs, dis, h2b, b2, out);

    // --- log softmax in place on d_out ---
    log_softmax64<<<(N_NODES + 3) / 4, 256, 0, stream>>>(out, N_NODES);
}